// Round 7
// baseline (2719.767 us; speedup 1.0000x reference)
//
#include <hip/hip_runtime.h>
#include <hip/hip_bf16.h>
#include <stdint.h>

#define T_TOK 4096
#define H_DIM 1024
#define F_DIM 4096
#define NE 8

typedef float    f32x4  __attribute__((ext_vector_type(4)));
typedef __bf16   bf16x8 __attribute__((ext_vector_type(8)));
typedef uint16_t u16x8  __attribute__((ext_vector_type(8)));

#define AS1 __attribute__((address_space(1)))
#define AS3 __attribute__((address_space(3)))

__device__ __forceinline__ uint16_t f2bf(float f) {
  return __builtin_bit_cast(uint16_t, __float2bfloat16(f));
}

__device__ __forceinline__ void gld16(const void* g, void* l) {
  __builtin_amdgcn_global_load_lds((const AS1 void*)g, (AS3 void*)l, 16, 0, 0);
}

// ---------------- router: logits (fp32, exact), top-2 gates, compaction, x->bf16
__global__ __launch_bounds__(256) void router_k(
    const float* __restrict__ x, const float* __restrict__ wr,
    float* __restrict__ logits, uint16_t* __restrict__ xb,
    int* __restrict__ pairTok, float* __restrict__ pairGate,
    int* __restrict__ cnt)
{
  const int lane = threadIdx.x & 63;
  const int wid  = threadIdx.x >> 6;
  const int t    = blockIdx.x * 4 + wid;

  const float* xp = x + (size_t)t * H_DIM + lane * 16;
  f32x4 xv[4];
#pragma unroll
  for (int i = 0; i < 4; ++i) xv[i] = *(const f32x4*)(xp + 4 * i);

  u16x8 o0, o1;
#pragma unroll
  for (int j = 0; j < 4; ++j) {
    o0[j] = f2bf(xv[0][j]); o0[j + 4] = f2bf(xv[1][j]);
    o1[j] = f2bf(xv[2][j]); o1[j + 4] = f2bf(xv[3][j]);
  }
  uint16_t* xbp = xb + (size_t)t * H_DIM + lane * 16;
  *(u16x8*)xbp       = o0;
  *(u16x8*)(xbp + 8) = o1;

  float s[NE];
#pragma unroll
  for (int e = 0; e < NE; ++e) {
    const float* wp = wr + e * H_DIM + lane * 16;
    float acc = 0.f;
#pragma unroll
    for (int i = 0; i < 4; ++i) {
      f32x4 wv = *(const f32x4*)(wp + 4 * i);
#pragma unroll
      for (int j = 0; j < 4; ++j) acc += xv[i][j] * wv[j];
    }
#pragma unroll
    for (int off = 32; off > 0; off >>= 1) acc += __shfl_xor(acc, off, 64);
    s[e] = acc;
  }

  if (lane == 0) {
#pragma unroll
    for (int e = 0; e < NE; ++e) logits[t * NE + e] = s[e];
    int e1 = 0;
#pragma unroll
    for (int e = 1; e < NE; ++e) if (s[e] > s[e1]) e1 = e;
    int e2 = (e1 == 0) ? 1 : 0;
#pragma unroll
    for (int e = 0; e < NE; ++e)
      if (e != e1 && e != e2 && s[e] > s[e2]) e2 = e;
    const float d  = s[e2] - s[e1];              // <= 0
    const float g1 = 1.f / (1.f + __expf(d));
    const float g2 = 1.f - g1;
    int i1 = atomicAdd(cnt + e1, 1);
    pairTok[e1 * T_TOK + i1] = t;  pairGate[e1 * T_TOK + i1] = g1;
    int i2 = atomicAdd(cnt + e2, 1);
    pairTok[e2 * T_TOK + i2] = t;  pairGate[e2 * T_TOK + i2] = g2;
  }
}

__global__ void prefix_k(const int* __restrict__ cnt, int* __restrict__ base) {
  if (threadIdx.x == 0) {
    int b = 0;
#pragma unroll
    for (int e = 0; e < NE; ++e) { base[e] = b; b += cnt[e]; }
  }
}

// ---------------- stage 1: h = silu(x@w1^T) * (x@w3^T)
// R5-proven inner loop, BM=512 x BN=64, BK=64, 8 waves (4M x 2N),
// wave tile 128x32 (unchanged). LDS 80 KB -> 2 blocks/CU, 16 waves/CU.
// Halves fp32-weight L3 re-reads vs R5 (2 m-blocks/expert instead of 4).
__global__ __launch_bounds__(512, 4) void ffn1_k(
    const uint16_t* __restrict__ xb, const float* __restrict__ w1,
    const float* __restrict__ w3, uint16_t* __restrict__ hbuf,
    const int* __restrict__ pairTok, const int* __restrict__ cnt,
    const int* __restrict__ base)
{
  const int e    = blockIdx.z;
  const int cnte = cnt[e];
  const int m0   = blockIdx.y * 512;
  if (m0 >= cnte) return;
  const int n0   = blockIdx.x * 64;
  const int tid  = threadIdx.x;
  const int lane = tid & 63;
  const int wid  = tid >> 6;           // 0..7
  const int wm   = (wid >> 1) * 128;   // 0,128,256,384
  const int wn   = (wid & 1) * 32;     // 0 or 32

  __shared__ __align__(16) uint16_t lsA [512 * 64];  // 64 KB
  __shared__ __align__(16) uint16_t lsB1[ 64 * 64];  //  8 KB
  __shared__ __align__(16) uint16_t lsB3[ 64 * 64];  //  8 KB

  const float* w1e = w1 + (size_t)e * F_DIM * H_DIM;
  const float* w3e = w3 + (size_t)e * F_DIM * H_DIM;

  // A: 4096 16B-chunks, 8/thread. Linear chunk c holds logical k-chunk
  // kc = (c&7)^(row&7) (pre-swizzled source, LDS stays linear).
  const uint16_t* asrc[8];
#pragma unroll
  for (int q = 0; q < 8; ++q) {
    const int c = q * 512 + tid;
    const int row = c >> 3, pos = c & 7;
    const int kc  = pos ^ (row & 7);
    int ar = m0 + row; if (ar >= cnte) ar = cnte - 1;
    const int tok = pairTok[e * T_TOK + ar];
    asrc[q] = xb + (size_t)tok * H_DIM + kc * 8;
  }
  // B: 512 chunks each, 1/thread, fp32 source reg-staged.
  const float* b1src;
  const float* b3src;
  int bdst;
  {
    const int c = tid;
    const int row = c >> 3, pos = c & 7;
    const int kc  = pos ^ (row & 7);
    bdst = c * 8;
    b1src = w1e + (size_t)(n0 + row) * H_DIM + kc * 8;
    b3src = w3e + (size_t)(n0 + row) * H_DIM + kc * 8;
  }

  const f32x4 fz = {0.f, 0.f, 0.f, 0.f};
  f32x4 acc1[8][2], acc3[8][2];
#pragma unroll
  for (int i = 0; i < 8; ++i)
#pragma unroll
    for (int j = 0; j < 2; ++j) { acc1[i][j] = fz; acc3[i][j] = fz; }

  for (int kt = 0; kt < H_DIM; kt += 64) {
    __syncthreads();
#pragma unroll
    for (int q = 0; q < 8; ++q)
      gld16(asrc[q] + kt, &lsA[(q * 512 + tid) * 8]);
    {
      const float* s1 = b1src + kt;
      const float* s3 = b3src + kt;
      f32x4 a0 = *(const f32x4*)s1;
      f32x4 a1 = *(const f32x4*)(s1 + 4);
      f32x4 c0 = *(const f32x4*)s3;
      f32x4 c1 = *(const f32x4*)(s3 + 4);
      u16x8 ob1, ob3;
#pragma unroll
      for (int j = 0; j < 4; ++j) {
        ob1[j] = f2bf(a0[j]); ob1[j + 4] = f2bf(a1[j]);
        ob3[j] = f2bf(c0[j]); ob3[j + 4] = f2bf(c1[j]);
      }
      *(u16x8*)&lsB1[bdst] = ob1;
      *(u16x8*)&lsB3[bdst] = ob3;
    }
    __syncthreads();
#pragma unroll
    for (int ks = 0; ks < 2; ++ks) {
      const int kg = ks * 4 + (lane >> 4);
      bf16x8 af[8], b1f[2], b3f[2];
#pragma unroll
      for (int i = 0; i < 8; ++i) {
        const int ar = wm + i * 16 + (lane & 15);
        af[i] = *(const bf16x8*)&lsA[ar * 64 + ((kg ^ (ar & 7)) * 8)];
      }
#pragma unroll
      for (int j = 0; j < 2; ++j) {
        const int br = wn + j * 16 + (lane & 15);
        b1f[j] = *(const bf16x8*)&lsB1[br * 64 + ((kg ^ (br & 7)) * 8)];
        b3f[j] = *(const bf16x8*)&lsB3[br * 64 + ((kg ^ (br & 7)) * 8)];
      }
#pragma unroll
      for (int i = 0; i < 8; ++i)
#pragma unroll
        for (int j = 0; j < 2; ++j) {
          acc1[i][j] = __builtin_amdgcn_mfma_f32_16x16x32_bf16(af[i], b1f[j], acc1[i][j], 0, 0, 0);
          acc3[i][j] = __builtin_amdgcn_mfma_f32_16x16x32_bf16(af[i], b3f[j], acc3[i][j], 0, 0, 0);
        }
    }
  }

  // epilogue: h = silu(a1)*a3 -> bf16. C/D: col=lane&15, row=(lane>>4)*4+r
  const int be = base[e];
#pragma unroll
  for (int i = 0; i < 8; ++i) {
#pragma unroll
    for (int r = 0; r < 4; ++r) {
      const int lrow = m0 + wm + i * 16 + (lane >> 4) * 4 + r;
      if (lrow < cnte) {
        uint16_t* hp = hbuf + (size_t)(be + lrow) * F_DIM + n0 + wn + (lane & 15);
#pragma unroll
        for (int j = 0; j < 2; ++j) {
          const float a  = acc1[i][j][r];
          const float hv = (a / (1.f + __expf(-a))) * acc3[i][j][r];
          hp[j * 16] = f2bf(hv);
        }
      }
    }
  }
}

// ---------------- stage 2: out[t] += gate * (h @ w2^T)
// BM=512 x BN=128, 8 waves (4M x 2N), wave tile 128x64. LDS 80 KB.
__global__ __launch_bounds__(512, 4) void ffn2_k(
    const uint16_t* __restrict__ hbuf, const float* __restrict__ w2,
    float* __restrict__ out, const int* __restrict__ pairTok,
    const float* __restrict__ pairGate, const int* __restrict__ cnt,
    const int* __restrict__ base)
{
  const int e    = blockIdx.z;
  const int cnte = cnt[e];
  const int m0   = blockIdx.y * 512;
  if (m0 >= cnte) return;
  const int n0   = blockIdx.x * 128;
  const int tid  = threadIdx.x;
  const int lane = tid & 63;
  const int wid  = tid >> 6;           // 0..7
  const int wm   = (wid >> 1) * 128;   // 0,128,256,384
  const int wn   = (wid & 1) * 64;     // 0 or 64

  __shared__ __align__(16) uint16_t lsA[512 * 64];   // 64 KB
  __shared__ __align__(16) uint16_t lsB[128 * 64];   // 16 KB

  const int be = base[e];
  const float* w2e = w2 + (size_t)e * H_DIM * F_DIM;

  const uint16_t* asrc[8];
#pragma unroll
  for (int q = 0; q < 8; ++q) {
    const int c = q * 512 + tid;
    const int row = c >> 3, pos = c & 7;
    const int kc  = pos ^ (row & 7);
    int rr = m0 + row; if (rr >= cnte) rr = cnte - 1;
    asrc[q] = hbuf + (size_t)(be + rr) * F_DIM + kc * 8;
  }
  const float* bsrc[2];
  int bdst[2];
#pragma unroll
  for (int q = 0; q < 2; ++q) {
    const int c = q * 512 + tid;
    const int row = c >> 3, pos = c & 7;
    const int kc  = pos ^ (row & 7);
    bdst[q] = c * 8;
    bsrc[q] = w2e + (size_t)(n0 + row) * F_DIM + kc * 8;
  }

  const f32x4 fz = {0.f, 0.f, 0.f, 0.f};
  f32x4 acc[8][4];
#pragma unroll
  for (int i = 0; i < 8; ++i)
#pragma unroll
    for (int j = 0; j < 4; ++j) acc[i][j] = fz;

  for (int kt = 0; kt < F_DIM; kt += 64) {
    __syncthreads();
#pragma unroll
    for (int q = 0; q < 8; ++q)
      gld16(asrc[q] + kt, &lsA[(q * 512 + tid) * 8]);
#pragma unroll
    for (int q = 0; q < 2; ++q) {
      const float* sb = bsrc[q] + kt;
      f32x4 b0 = *(const f32x4*)sb;
      f32x4 b1 = *(const f32x4*)(sb + 4);
      u16x8 ob;
#pragma unroll
      for (int j = 0; j < 4; ++j) { ob[j] = f2bf(b0[j]); ob[j + 4] = f2bf(b1[j]); }
      *(u16x8*)&lsB[bdst[q]] = ob;
    }
    __syncthreads();
#pragma unroll
    for (int ks = 0; ks < 2; ++ks) {
      const int kg = ks * 4 + (lane >> 4);
      bf16x8 af[8], bf[4];
#pragma unroll
      for (int i = 0; i < 8; ++i) {
        const int ar = wm + i * 16 + (lane & 15);
        af[i] = *(const bf16x8*)&lsA[ar * 64 + ((kg ^ (ar & 7)) * 8)];
      }
#pragma unroll
      for (int j = 0; j < 4; ++j) {
        const int br = wn + j * 16 + (lane & 15);
        bf[j] = *(const bf16x8*)&lsB[br * 64 + ((kg ^ (br & 7)) * 8)];
      }
#pragma unroll
      for (int i = 0; i < 8; ++i)
#pragma unroll
        for (int j = 0; j < 4; ++j)
          acc[i][j] = __builtin_amdgcn_mfma_f32_16x16x32_bf16(af[i], bf[j], acc[i][j], 0, 0, 0);
    }
  }

  // epilogue: gate-scale and accumulate into out (2 experts/token -> atomics)
#pragma unroll
  for (int i = 0; i < 8; ++i) {
#pragma unroll
    for (int r = 0; r < 4; ++r) {
      const int lrow = m0 + wm + i * 16 + (lane >> 4) * 4 + r;
      if (lrow < cnte) {
        const int   t = pairTok [e * T_TOK + lrow];
        const float g = pairGate[e * T_TOK + lrow];
        float* op = out + (size_t)t * H_DIM + n0 + wn + (lane & 15);
#pragma unroll
        for (int j = 0; j < 4; ++j)
          unsafeAtomicAdd(op + j * 16, g * acc[i][j][r]);
      }
    }
  }
}

extern "C" void kernel_launch(void* const* d_in, const int* in_sizes, int n_in,
                              void* d_out, int out_size, void* d_ws, size_t ws_size,
                              hipStream_t stream)
{
  const float* x  = (const float*)d_in[0];
  const float* wr = (const float*)d_in[1];
  const float* w1 = (const float*)d_in[2];
  const float* w2 = (const float*)d_in[3];
  const float* w3 = (const float*)d_in[4];
  float* out    = (float*)d_out;
  float* logits = out + (size_t)T_TOK * H_DIM;

  uint8_t* ws = (uint8_t*)d_ws;
  const size_t XB_OFF   = 0;                                        // bf16 x   [T][H]   8 MB
  const size_t HB_OFF   = XB_OFF + (size_t)T_TOK * H_DIM * 2;       // bf16 h   [2T][F] 64 MB
  const size_t PT_OFF   = HB_OFF + (size_t)2 * T_TOK * F_DIM * 2;
  const size_t PG_OFF   = PT_OFF + (size_t)NE * T_TOK * 4;
  const size_t CNT_OFF  = PG_OFF + (size_t)NE * T_TOK * 4;
  const size_t BASE_OFF = CNT_OFF + 64;
  const size_t NEED     = BASE_OFF + 64;
  if (ws_size < NEED) return;

  uint16_t* xb      = (uint16_t*)(ws + XB_OFF);
  uint16_t* hb      = (uint16_t*)(ws + HB_OFF);
  int*      pairTok = (int*)(ws + PT_OFF);
  float*    pairGate= (float*)(ws + PG_OFF);
  int*      cnt     = (int*)(ws + CNT_OFF);
  int*      basep   = (int*)(ws + BASE_OFF);

  hipMemsetAsync(out, 0, (size_t)T_TOK * H_DIM * sizeof(float), stream);
  hipMemsetAsync(cnt, 0, 64, stream);
  router_k<<<T_TOK / 4, 256, 0, stream>>>(x, wr, logits, xb, pairTok, pairGate, cnt);
  prefix_k<<<1, 64, 0, stream>>>(cnt, basep);
  // grid.y covers worst-case cnte (up to T_TOK); blocks beyond cnte exit early
  ffn1_k<<<dim3(F_DIM / 64, T_TOK / 512, NE), 512, 0, stream>>>(xb, w1, w3, hb, pairTok, cnt, basep);
  ffn2_k<<<dim3(H_DIM / 128, T_TOK / 512, NE), 512, 0, stream>>>(hb, w2, out, pairTok, pairGate, cnt, basep);
}

// Round 8
// 547.404 us; speedup vs baseline: 4.9685x; 4.9685x over previous
//
#include <hip/hip_runtime.h>
#include <hip/hip_bf16.h>
#include <stdint.h>

#define T_TOK 4096
#define H_DIM 1024
#define F_DIM 4096
#define NE 8

typedef float    f32x4  __attribute__((ext_vector_type(4)));
typedef __bf16   bf16x8 __attribute__((ext_vector_type(8)));
typedef uint16_t u16x8  __attribute__((ext_vector_type(8)));

#define AS1 __attribute__((address_space(1)))
#define AS3 __attribute__((address_space(3)))

__device__ __forceinline__ uint16_t f2bf(float f) {
  return __builtin_bit_cast(uint16_t, __float2bfloat16(f));
}

__device__ __forceinline__ void gld16(const void* g, void* l) {
  __builtin_amdgcn_global_load_lds((const AS1 void*)g, (AS3 void*)l, 16, 0, 0);
}

// ---------------- router: logits (fp32, exact), top-2 gates, compaction, x->bf16
__global__ __launch_bounds__(256) void router_k(
    const float* __restrict__ x, const float* __restrict__ wr,
    float* __restrict__ logits, uint16_t* __restrict__ xb,
    int* __restrict__ pairTok, float* __restrict__ pairGate,
    int* __restrict__ cnt)
{
  const int lane = threadIdx.x & 63;
  const int wid  = threadIdx.x >> 6;
  const int t    = blockIdx.x * 4 + wid;

  const float* xp = x + (size_t)t * H_DIM + lane * 16;
  f32x4 xv[4];
#pragma unroll
  for (int i = 0; i < 4; ++i) xv[i] = *(const f32x4*)(xp + 4 * i);

  u16x8 o0, o1;
#pragma unroll
  for (int j = 0; j < 4; ++j) {
    o0[j] = f2bf(xv[0][j]); o0[j + 4] = f2bf(xv[1][j]);
    o1[j] = f2bf(xv[2][j]); o1[j + 4] = f2bf(xv[3][j]);
  }
  uint16_t* xbp = xb + (size_t)t * H_DIM + lane * 16;
  *(u16x8*)xbp       = o0;
  *(u16x8*)(xbp + 8) = o1;

  float s[NE];
#pragma unroll
  for (int e = 0; e < NE; ++e) {
    const float* wp = wr + e * H_DIM + lane * 16;
    float acc = 0.f;
#pragma unroll
    for (int i = 0; i < 4; ++i) {
      f32x4 wv = *(const f32x4*)(wp + 4 * i);
#pragma unroll
      for (int j = 0; j < 4; ++j) acc += xv[i][j] * wv[j];
    }
#pragma unroll
    for (int off = 32; off > 0; off >>= 1) acc += __shfl_xor(acc, off, 64);
    s[e] = acc;
  }

  if (lane == 0) {
#pragma unroll
    for (int e = 0; e < NE; ++e) logits[t * NE + e] = s[e];
    int e1 = 0;
#pragma unroll
    for (int e = 1; e < NE; ++e) if (s[e] > s[e1]) e1 = e;
    int e2 = (e1 == 0) ? 1 : 0;
#pragma unroll
    for (int e = 0; e < NE; ++e)
      if (e != e1 && e != e2 && s[e] > s[e2]) e2 = e;
    const float d  = s[e2] - s[e1];              // <= 0
    const float g1 = 1.f / (1.f + __expf(d));
    const float g2 = 1.f - g1;
    int i1 = atomicAdd(cnt + e1, 1);
    pairTok[e1 * T_TOK + i1] = t;  pairGate[e1 * T_TOK + i1] = g1;
    int i2 = atomicAdd(cnt + e2, 1);
    pairTok[e2 * T_TOK + i2] = t;  pairGate[e2 * T_TOK + i2] = g2;
  }
}

__global__ void prefix_k(const int* __restrict__ cnt, int* __restrict__ base) {
  if (threadIdx.x == 0) {
    int b = 0;
#pragma unroll
    for (int e = 0; e < NE; ++e) { base[e] = b; b += cnt[e]; }
  }
}

// ---------------- stage 1: h = silu(x@w1^T) * (x@w3^T)
// BM=256 x BN=128, BK=64, 512 threads = 8 waves (2M x 4N), wave tile 128x32
// (per-thread work and VGPR identical to the verified R5 kernel: dual acc[8][2]).
// LDS 64 KB (A 32K + B1 16K + B3 16K) -> 2 blocks/CU by LDS; VGPR ~112.
// A-traffic halves vs R5 (32 n-blocks re-read A instead of 64).
__global__ __launch_bounds__(512, 2) void ffn1_k(
    const uint16_t* __restrict__ xb, const float* __restrict__ w1,
    const float* __restrict__ w3, uint16_t* __restrict__ hbuf,
    const int* __restrict__ pairTok, const int* __restrict__ cnt,
    const int* __restrict__ base)
{
  const int e    = blockIdx.z;
  const int cnte = cnt[e];
  const int m0   = blockIdx.y * 256;
  if (m0 >= cnte) return;
  const int n0   = blockIdx.x * 128;
  const int tid  = threadIdx.x;
  const int lane = tid & 63;
  const int wid  = tid >> 6;           // 0..7
  const int wm   = (wid >> 2) * 128;   // 0 or 128
  const int wn   = (wid & 3) * 32;     // 0,32,64,96

  __shared__ __align__(16) uint16_t lsA [256 * 64];  // 32 KB
  __shared__ __align__(16) uint16_t lsB1[128 * 64];  // 16 KB
  __shared__ __align__(16) uint16_t lsB3[128 * 64];  // 16 KB

  const float* w1e = w1 + (size_t)e * F_DIM * H_DIM;
  const float* w3e = w3 + (size_t)e * F_DIM * H_DIM;

  // A: 2048 16B-chunks, 4/thread. Linear chunk c holds logical k-chunk
  // kc = (c&7)^(row&7) (pre-swizzled source, LDS stays linear).
  const uint16_t* asrc[4];
#pragma unroll
  for (int q = 0; q < 4; ++q) {
    const int c = q * 512 + tid;
    const int row = c >> 3, pos = c & 7;
    const int kc  = pos ^ (row & 7);
    int ar = m0 + row; if (ar >= cnte) ar = cnte - 1;
    const int tok = pairTok[e * T_TOK + ar];
    asrc[q] = xb + (size_t)tok * H_DIM + kc * 8;
  }
  // B: 1024 chunks each, 2/thread, fp32 source reg-staged.
  const float* b1src[2];
  const float* b3src[2];
  int bdst[2];
#pragma unroll
  for (int q = 0; q < 2; ++q) {
    const int c = q * 512 + tid;
    const int row = c >> 3, pos = c & 7;
    const int kc  = pos ^ (row & 7);
    bdst[q] = c * 8;
    b1src[q] = w1e + (size_t)(n0 + row) * H_DIM + kc * 8;
    b3src[q] = w3e + (size_t)(n0 + row) * H_DIM + kc * 8;
  }

  const f32x4 fz = {0.f, 0.f, 0.f, 0.f};
  f32x4 acc1[8][2], acc3[8][2];
#pragma unroll
  for (int i = 0; i < 8; ++i)
#pragma unroll
    for (int j = 0; j < 2; ++j) { acc1[i][j] = fz; acc3[i][j] = fz; }

  for (int kt = 0; kt < H_DIM; kt += 64) {
    __syncthreads();
#pragma unroll
    for (int q = 0; q < 4; ++q)
      gld16(asrc[q] + kt, &lsA[(q * 512 + tid) * 8]);
#pragma unroll
    for (int q = 0; q < 2; ++q) {
      const float* s1 = b1src[q] + kt;
      const float* s3 = b3src[q] + kt;
      f32x4 a0 = *(const f32x4*)s1;
      f32x4 a1 = *(const f32x4*)(s1 + 4);
      f32x4 c0 = *(const f32x4*)s3;
      f32x4 c1 = *(const f32x4*)(s3 + 4);
      u16x8 ob1, ob3;
#pragma unroll
      for (int j = 0; j < 4; ++j) {
        ob1[j] = f2bf(a0[j]); ob1[j + 4] = f2bf(a1[j]);
        ob3[j] = f2bf(c0[j]); ob3[j + 4] = f2bf(c1[j]);
      }
      *(u16x8*)&lsB1[bdst[q]] = ob1;
      *(u16x8*)&lsB3[bdst[q]] = ob3;
    }
    __syncthreads();
#pragma unroll
    for (int ks = 0; ks < 2; ++ks) {
      const int kg = ks * 4 + (lane >> 4);
      bf16x8 af[8], b1f[2], b3f[2];
#pragma unroll
      for (int i = 0; i < 8; ++i) {
        const int ar = wm + i * 16 + (lane & 15);
        af[i] = *(const bf16x8*)&lsA[ar * 64 + ((kg ^ (ar & 7)) * 8)];
      }
#pragma unroll
      for (int j = 0; j < 2; ++j) {
        const int br = wn + j * 16 + (lane & 15);
        b1f[j] = *(const bf16x8*)&lsB1[br * 64 + ((kg ^ (br & 7)) * 8)];
        b3f[j] = *(const bf16x8*)&lsB3[br * 64 + ((kg ^ (br & 7)) * 8)];
      }
#pragma unroll
      for (int i = 0; i < 8; ++i)
#pragma unroll
        for (int j = 0; j < 2; ++j) {
          acc1[i][j] = __builtin_amdgcn_mfma_f32_16x16x32_bf16(af[i], b1f[j], acc1[i][j], 0, 0, 0);
          acc3[i][j] = __builtin_amdgcn_mfma_f32_16x16x32_bf16(af[i], b3f[j], acc3[i][j], 0, 0, 0);
        }
    }
  }

  // epilogue: h = silu(a1)*a3 -> bf16. C/D: col=lane&15, row=(lane>>4)*4+r
  const int be = base[e];
#pragma unroll
  for (int i = 0; i < 8; ++i) {
#pragma unroll
    for (int r = 0; r < 4; ++r) {
      const int lrow = m0 + wm + i * 16 + (lane >> 4) * 4 + r;
      if (lrow < cnte) {
        uint16_t* hp = hbuf + (size_t)(be + lrow) * F_DIM + n0 + wn + (lane & 15);
#pragma unroll
        for (int j = 0; j < 2; ++j) {
          const float a  = acc1[i][j][r];
          const float hv = (a / (1.f + __expf(-a))) * acc3[i][j][r];
          hp[j * 16] = f2bf(hv);
        }
      }
    }
  }
}

// ---------------- stage 2: out[t] += gate * (h @ w2^T)
// R5-exact proven kernel: BM=256 x BN=128, 256 threads, 4 waves (2M x 2N),
// wave tile 128x64, single acc[8][4]. LDS 48 KB.
__global__ __launch_bounds__(256, 2) void ffn2_k(
    const uint16_t* __restrict__ hbuf, const float* __restrict__ w2,
    float* __restrict__ out, const int* __restrict__ pairTok,
    const float* __restrict__ pairGate, const int* __restrict__ cnt,
    const int* __restrict__ base)
{
  const int e    = blockIdx.z;
  const int cnte = cnt[e];
  const int m0   = blockIdx.y * 256;
  if (m0 >= cnte) return;
  const int n0   = blockIdx.x * 128;
  const int tid  = threadIdx.x;
  const int lane = tid & 63;
  const int wid  = tid >> 6;
  const int wm   = (wid >> 1) * 128;   // 0 or 128
  const int wn   = (wid & 1) * 64;     // 0 or 64

  __shared__ __align__(16) uint16_t lsA[256 * 64];   // 32 KB
  __shared__ __align__(16) uint16_t lsB[128 * 64];   // 16 KB

  const int be = base[e];
  const float* w2e = w2 + (size_t)e * H_DIM * F_DIM;

  const uint16_t* asrc[8];
#pragma unroll
  for (int q = 0; q < 8; ++q) {
    const int c = q * 256 + tid;
    const int row = c >> 3, pos = c & 7;
    const int kc  = pos ^ (row & 7);
    int rr = m0 + row; if (rr >= cnte) rr = cnte - 1;
    asrc[q] = hbuf + (size_t)(be + rr) * F_DIM + kc * 8;
  }
  const float* bsrc[4];
  int bdst[4];
#pragma unroll
  for (int q = 0; q < 4; ++q) {
    const int c = q * 256 + tid;
    const int row = c >> 3, pos = c & 7;
    const int kc  = pos ^ (row & 7);
    bdst[q] = c * 8;
    bsrc[q] = w2e + (size_t)(n0 + row) * F_DIM + kc * 8;
  }

  const f32x4 fz = {0.f, 0.f, 0.f, 0.f};
  f32x4 acc[8][4];
#pragma unroll
  for (int i = 0; i < 8; ++i)
#pragma unroll
    for (int j = 0; j < 4; ++j) acc[i][j] = fz;

  for (int kt = 0; kt < F_DIM; kt += 64) {
    __syncthreads();
#pragma unroll
    for (int q = 0; q < 8; ++q)
      gld16(asrc[q] + kt, &lsA[(q * 256 + tid) * 8]);
#pragma unroll
    for (int q = 0; q < 4; ++q) {
      const float* sb = bsrc[q] + kt;
      f32x4 b0 = *(const f32x4*)sb;
      f32x4 b1 = *(const f32x4*)(sb + 4);
      u16x8 ob;
#pragma unroll
      for (int j = 0; j < 4; ++j) { ob[j] = f2bf(b0[j]); ob[j + 4] = f2bf(b1[j]); }
      *(u16x8*)&lsB[bdst[q]] = ob;
    }
    __syncthreads();
#pragma unroll
    for (int ks = 0; ks < 2; ++ks) {
      const int kg = ks * 4 + (lane >> 4);
      bf16x8 af[8], bf[4];
#pragma unroll
      for (int i = 0; i < 8; ++i) {
        const int ar = wm + i * 16 + (lane & 15);
        af[i] = *(const bf16x8*)&lsA[ar * 64 + ((kg ^ (ar & 7)) * 8)];
      }
#pragma unroll
      for (int j = 0; j < 4; ++j) {
        const int br = wn + j * 16 + (lane & 15);
        bf[j] = *(const bf16x8*)&lsB[br * 64 + ((kg ^ (br & 7)) * 8)];
      }
#pragma unroll
      for (int i = 0; i < 8; ++i)
#pragma unroll
        for (int j = 0; j < 4; ++j)
          acc[i][j] = __builtin_amdgcn_mfma_f32_16x16x32_bf16(af[i], bf[j], acc[i][j], 0, 0, 0);
    }
  }

  // epilogue: gate-scale and accumulate into out (2 experts/token -> atomics)
#pragma unroll
  for (int i = 0; i < 8; ++i) {
#pragma unroll
    for (int r = 0; r < 4; ++r) {
      const int lrow = m0 + wm + i * 16 + (lane >> 4) * 4 + r;
      if (lrow < cnte) {
        const int   t = pairTok [e * T_TOK + lrow];
        const float g = pairGate[e * T_TOK + lrow];
        float* op = out + (size_t)t * H_DIM + n0 + wn + (lane & 15);
#pragma unroll
        for (int j = 0; j < 4; ++j)
          unsafeAtomicAdd(op + j * 16, g * acc[i][j][r]);
      }
    }
  }
}

extern "C" void kernel_launch(void* const* d_in, const int* in_sizes, int n_in,
                              void* d_out, int out_size, void* d_ws, size_t ws_size,
                              hipStream_t stream)
{
  const float* x  = (const float*)d_in[0];
  const float* wr = (const float*)d_in[1];
  const float* w1 = (const float*)d_in[2];
  const float* w2 = (const float*)d_in[3];
  const float* w3 = (const float*)d_in[4];
  float* out    = (float*)d_out;
  float* logits = out + (size_t)T_TOK * H_DIM;

  uint8_t* ws = (uint8_t*)d_ws;
  const size_t XB_OFF   = 0;                                        // bf16 x   [T][H]   8 MB
  const size_t HB_OFF   = XB_OFF + (size_t)T_TOK * H_DIM * 2;       // bf16 h   [2T][F] 64 MB
  const size_t PT_OFF   = HB_OFF + (size_t)2 * T_TOK * F_DIM * 2;
  const size_t PG_OFF   = PT_OFF + (size_t)NE * T_TOK * 4;
  const size_t CNT_OFF  = PG_OFF + (size_t)NE * T_TOK * 4;
  const size_t BASE_OFF = CNT_OFF + 64;
  const size_t NEED     = BASE_OFF + 64;
  if (ws_size < NEED) return;

  uint16_t* xb      = (uint16_t*)(ws + XB_OFF);
  uint16_t* hb      = (uint16_t*)(ws + HB_OFF);
  int*      pairTok = (int*)(ws + PT_OFF);
  float*    pairGate= (float*)(ws + PG_OFF);
  int*      cnt     = (int*)(ws + CNT_OFF);
  int*      basep   = (int*)(ws + BASE_OFF);

  hipMemsetAsync(out, 0, (size_t)T_TOK * H_DIM * sizeof(float), stream);
  hipMemsetAsync(cnt, 0, 64, stream);
  router_k<<<T_TOK / 4, 256, 0, stream>>>(x, wr, logits, xb, pairTok, pairGate, cnt);
  prefix_k<<<1, 64, 0, stream>>>(cnt, basep);
  // grid.y covers worst-case cnte (up to T_TOK); blocks beyond cnte exit early
  ffn1_k<<<dim3(F_DIM / 128, T_TOK / 256, NE), 512, 0, stream>>>(xb, w1, w3, hb, pairTok, cnt, basep);
  ffn2_k<<<dim3(H_DIM / 128, T_TOK / 256, NE), 256, 0, stream>>>(hb, w2, out, pairTok, pairGate, cnt, basep);
}

// Round 9
// 470.212 us; speedup vs baseline: 5.7841x; 1.1642x over previous
//
#include <hip/hip_runtime.h>
#include <hip/hip_bf16.h>
#include <stdint.h>

#define T_TOK 4096
#define H_DIM 1024
#define F_DIM 4096
#define NE 8
#define MG_BLKS 40   // ceil((2T + 8*255)/256): max 256-aligned m-chunks

typedef float    f32x4  __attribute__((ext_vector_type(4)));
typedef __bf16   bf16x8 __attribute__((ext_vector_type(8)));
typedef uint16_t u16x8  __attribute__((ext_vector_type(8)));

#define AS1 __attribute__((address_space(1)))
#define AS3 __attribute__((address_space(3)))

__device__ __forceinline__ uint16_t f2bf(float f) {
  return __builtin_bit_cast(uint16_t, __float2bfloat16(f));
}

__device__ __forceinline__ void gld16(const void* g, void* l) {
  __builtin_amdgcn_global_load_lds((const AS1 void*)g, (AS3 void*)l, 16, 0, 0);
}

// ---------------- router: logits (fp32, exact), top-2 gates, compaction, x->bf16
__global__ __launch_bounds__(256) void router_k(
    const float* __restrict__ x, const float* __restrict__ wr,
    float* __restrict__ logits, uint16_t* __restrict__ xb,
    int* __restrict__ pairTok, float* __restrict__ pairGate,
    int* __restrict__ tokSlot, int* __restrict__ cnt)
{
  const int lane = threadIdx.x & 63;
  const int wid  = threadIdx.x >> 6;
  const int t    = blockIdx.x * 4 + wid;

  const float* xp = x + (size_t)t * H_DIM + lane * 16;
  f32x4 xv[4];
#pragma unroll
  for (int i = 0; i < 4; ++i) xv[i] = *(const f32x4*)(xp + 4 * i);

  u16x8 o0, o1;
#pragma unroll
  for (int j = 0; j < 4; ++j) {
    o0[j] = f2bf(xv[0][j]); o0[j + 4] = f2bf(xv[1][j]);
    o1[j] = f2bf(xv[2][j]); o1[j + 4] = f2bf(xv[3][j]);
  }
  uint16_t* xbp = xb + (size_t)t * H_DIM + lane * 16;
  *(u16x8*)xbp       = o0;
  *(u16x8*)(xbp + 8) = o1;

  float s[NE];
#pragma unroll
  for (int e = 0; e < NE; ++e) {
    const float* wp = wr + e * H_DIM + lane * 16;
    float acc = 0.f;
#pragma unroll
    for (int i = 0; i < 4; ++i) {
      f32x4 wv = *(const f32x4*)(wp + 4 * i);
#pragma unroll
      for (int j = 0; j < 4; ++j) acc += xv[i][j] * wv[j];
    }
#pragma unroll
    for (int off = 32; off > 0; off >>= 1) acc += __shfl_xor(acc, off, 64);
    s[e] = acc;
  }

  if (lane == 0) {
#pragma unroll
    for (int e = 0; e < NE; ++e) logits[t * NE + e] = s[e];
    int e1 = 0;
#pragma unroll
    for (int e = 1; e < NE; ++e) if (s[e] > s[e1]) e1 = e;
    int e2 = (e1 == 0) ? 1 : 0;
#pragma unroll
    for (int e = 0; e < NE; ++e)
      if (e != e1 && e != e2 && s[e] > s[e2]) e2 = e;
    const float d  = s[e2] - s[e1];              // <= 0
    const float g1 = 1.f / (1.f + __expf(d));
    const float g2 = 1.f - g1;
    int i1 = atomicAdd(cnt + e1, 1);
    pairTok[e1 * T_TOK + i1] = t;  pairGate[e1 * T_TOK + i1] = g1;
    int i2 = atomicAdd(cnt + e2, 1);
    pairTok[e2 * T_TOK + i2] = t;  pairGate[e2 * T_TOK + i2] = g2;
    int4 sl; sl.x = e1; sl.y = i1; sl.z = e2; sl.w = i2;
    ((int4*)tokSlot)[t] = sl;
  }
}

// ---------------- prefix: 256-aligned bases; base[NE] = padded total
__global__ void prefix_k(const int* __restrict__ cnt, int* __restrict__ base) {
  if (threadIdx.x == 0) {
    int b = 0;
#pragma unroll
    for (int e = 0; e < NE; ++e) { base[e] = b; b += (cnt[e] + 255) & ~255; }
    base[NE] = b;
  }
}

// ---------------- stage 1: h = gate * silu(x@w1^T) * (x@w3^T)
// R5-exact inner loop (BM=256 x BN=64, BK=64, XOR swizzle, gld16-A,
// reg-staged fp32 B, 4 waves, wave tile 128x32, dual acc). Dense m-grid via
// aligned bases (every block live, one expert per block). Gate fused here.
__global__ __launch_bounds__(256, 2) void ffn1_k(
    const uint16_t* __restrict__ xb, const float* __restrict__ w1,
    const float* __restrict__ w3, uint16_t* __restrict__ hbuf,
    const int* __restrict__ pairTok, const float* __restrict__ pairGate,
    const int* __restrict__ cnt, const int* __restrict__ base)
{
  const int mg0 = blockIdx.y * 256;          // global padded h row
  if (mg0 >= base[NE]) return;
  int e = 0;
#pragma unroll
  for (int k = 1; k < NE; ++k) if (mg0 >= base[k]) e = k;
  const int m0   = mg0 - base[e];            // local row; provably < cnte
  const int cnte = cnt[e];
  const int n0   = blockIdx.x * 64;
  const int tid  = threadIdx.x;
  const int lane = tid & 63;
  const int wid  = tid >> 6;
  const int wm   = (wid >> 1) * 128;   // 0 or 128
  const int wn   = (wid & 1) * 32;     // 0 or 32

  __shared__ __align__(16) uint16_t lsA [256 * 64];  // 32 KB
  __shared__ __align__(16) uint16_t lsB1[ 64 * 64];  //  8 KB
  __shared__ __align__(16) uint16_t lsB3[ 64 * 64];  //  8 KB
  __shared__ float lsG[256];                          //  1 KB

  {
    const int rr = m0 + tid;
    lsG[tid] = (rr < cnte) ? pairGate[e * T_TOK + rr] : 0.f;
  }

  const float* w1e = w1 + (size_t)e * F_DIM * H_DIM;
  const float* w3e = w3 + (size_t)e * F_DIM * H_DIM;

  const uint16_t* asrc[8];
#pragma unroll
  for (int q = 0; q < 8; ++q) {
    const int c = q * 256 + tid;
    const int row = c >> 3, pos = c & 7;
    const int kc  = pos ^ (row & 7);
    int ar = m0 + row; if (ar >= cnte) ar = cnte - 1;
    const int tok = pairTok[e * T_TOK + ar];
    asrc[q] = xb + (size_t)tok * H_DIM + kc * 8;
  }
  const float* b1src[2];
  const float* b3src[2];
  int bdst[2];
#pragma unroll
  for (int q = 0; q < 2; ++q) {
    const int c = q * 256 + tid;
    const int row = c >> 3, pos = c & 7;
    const int kc  = pos ^ (row & 7);
    bdst[q] = c * 8;
    b1src[q] = w1e + (size_t)(n0 + row) * H_DIM + kc * 8;
    b3src[q] = w3e + (size_t)(n0 + row) * H_DIM + kc * 8;
  }

  const f32x4 fz = {0.f, 0.f, 0.f, 0.f};
  f32x4 acc1[8][2], acc3[8][2];
#pragma unroll
  for (int i = 0; i < 8; ++i)
#pragma unroll
    for (int j = 0; j < 2; ++j) { acc1[i][j] = fz; acc3[i][j] = fz; }

  for (int kt = 0; kt < H_DIM; kt += 64) {
    __syncthreads();
#pragma unroll
    for (int q = 0; q < 8; ++q)
      gld16(asrc[q] + kt, &lsA[(q * 256 + tid) * 8]);
#pragma unroll
    for (int q = 0; q < 2; ++q) {
      const float* s1 = b1src[q] + kt;
      const float* s3 = b3src[q] + kt;
      f32x4 a0 = *(const f32x4*)s1;
      f32x4 a1 = *(const f32x4*)(s1 + 4);
      f32x4 c0 = *(const f32x4*)s3;
      f32x4 c1 = *(const f32x4*)(s3 + 4);
      u16x8 ob1, ob3;
#pragma unroll
      for (int j = 0; j < 4; ++j) {
        ob1[j] = f2bf(a0[j]); ob1[j + 4] = f2bf(a1[j]);
        ob3[j] = f2bf(c0[j]); ob3[j + 4] = f2bf(c1[j]);
      }
      *(u16x8*)&lsB1[bdst[q]] = ob1;
      *(u16x8*)&lsB3[bdst[q]] = ob3;
    }
    __syncthreads();
#pragma unroll
    for (int ks = 0; ks < 2; ++ks) {
      const int kg = ks * 4 + (lane >> 4);
      bf16x8 af[8], b1f[2], b3f[2];
#pragma unroll
      for (int i = 0; i < 8; ++i) {
        const int ar = wm + i * 16 + (lane & 15);
        af[i] = *(const bf16x8*)&lsA[ar * 64 + ((kg ^ (ar & 7)) * 8)];
      }
#pragma unroll
      for (int j = 0; j < 2; ++j) {
        const int br = wn + j * 16 + (lane & 15);
        b1f[j] = *(const bf16x8*)&lsB1[br * 64 + ((kg ^ (br & 7)) * 8)];
        b3f[j] = *(const bf16x8*)&lsB3[br * 64 + ((kg ^ (br & 7)) * 8)];
      }
#pragma unroll
      for (int i = 0; i < 8; ++i)
#pragma unroll
        for (int j = 0; j < 2; ++j) {
          acc1[i][j] = __builtin_amdgcn_mfma_f32_16x16x32_bf16(af[i], b1f[j], acc1[i][j], 0, 0, 0);
          acc3[i][j] = __builtin_amdgcn_mfma_f32_16x16x32_bf16(af[i], b3f[j], acc3[i][j], 0, 0, 0);
        }
    }
  }

  // epilogue: h = g * silu(a1) * a3 -> bf16. C/D: col=lane&15, row=(lane>>4)*4+r
  const int be = base[e];
#pragma unroll
  for (int i = 0; i < 8; ++i) {
#pragma unroll
    for (int r = 0; r < 4; ++r) {
      const int lrow = m0 + wm + i * 16 + (lane >> 4) * 4 + r;
      if (lrow < cnte) {
        const float g = lsG[lrow - m0];
        uint16_t* hp = hbuf + (size_t)(be + lrow) * F_DIM + n0 + wn + (lane & 15);
#pragma unroll
        for (int j = 0; j < 2; ++j) {
          const float a  = acc1[i][j][r];
          const float hv = g * (a / (1.f + __expf(-a))) * acc3[i][j][r];
          hp[j * 16] = f2bf(hv);
        }
      }
    }
  }
}

// ---------------- stage 2: y[row] = h[row] @ w2^T  (bf16 stores, no atomics)
// R5-exact inner loop (BM=256 x BN=128, 4 waves, wave tile 128x64). Dense m-grid.
__global__ __launch_bounds__(256, 2) void ffn2_k(
    const uint16_t* __restrict__ hbuf, const float* __restrict__ w2,
    uint16_t* __restrict__ y, const int* __restrict__ cnt,
    const int* __restrict__ base)
{
  const int mg0 = blockIdx.y * 256;
  if (mg0 >= base[NE]) return;
  int e = 0;
#pragma unroll
  for (int k = 1; k < NE; ++k) if (mg0 >= base[k]) e = k;
  const int m0   = mg0 - base[e];
  const int cnte = cnt[e];
  const int n0   = blockIdx.x * 128;
  const int tid  = threadIdx.x;
  const int lane = tid & 63;
  const int wid  = tid >> 6;
  const int wm   = (wid >> 1) * 128;   // 0 or 128
  const int wn   = (wid & 1) * 64;     // 0 or 64

  __shared__ __align__(16) uint16_t lsA[256 * 64];   // 32 KB
  __shared__ __align__(16) uint16_t lsB[128 * 64];   // 16 KB

  const int be = base[e];
  const float* w2e = w2 + (size_t)e * H_DIM * F_DIM;

  const uint16_t* asrc[8];
#pragma unroll
  for (int q = 0; q < 8; ++q) {
    const int c = q * 256 + tid;
    const int row = c >> 3, pos = c & 7;
    const int kc  = pos ^ (row & 7);
    int rr = m0 + row; if (rr >= cnte) rr = cnte - 1;
    asrc[q] = hbuf + (size_t)(be + rr) * F_DIM + kc * 8;
  }
  const float* bsrc[4];
  int bdst[4];
#pragma unroll
  for (int q = 0; q < 4; ++q) {
    const int c = q * 256 + tid;
    const int row = c >> 3, pos = c & 7;
    const int kc  = pos ^ (row & 7);
    bdst[q] = c * 8;
    bsrc[q] = w2e + (size_t)(n0 + row) * F_DIM + kc * 8;
  }

  const f32x4 fz = {0.f, 0.f, 0.f, 0.f};
  f32x4 acc[8][4];
#pragma unroll
  for (int i = 0; i < 8; ++i)
#pragma unroll
    for (int j = 0; j < 4; ++j) acc[i][j] = fz;

  for (int kt = 0; kt < F_DIM; kt += 64) {
    __syncthreads();
#pragma unroll
    for (int q = 0; q < 8; ++q)
      gld16(asrc[q] + kt, &lsA[(q * 256 + tid) * 8]);
#pragma unroll
    for (int q = 0; q < 4; ++q) {
      const float* sb = bsrc[q] + kt;
      f32x4 b0 = *(const f32x4*)sb;
      f32x4 b1 = *(const f32x4*)(sb + 4);
      u16x8 ob;
#pragma unroll
      for (int j = 0; j < 4; ++j) { ob[j] = f2bf(b0[j]); ob[j + 4] = f2bf(b1[j]); }
      *(u16x8*)&lsB[bdst[q]] = ob;
    }
    __syncthreads();
#pragma unroll
    for (int ks = 0; ks < 2; ++ks) {
      const int kg = ks * 4 + (lane >> 4);
      bf16x8 af[8], bf[4];
#pragma unroll
      for (int i = 0; i < 8; ++i) {
        const int ar = wm + i * 16 + (lane & 15);
        af[i] = *(const bf16x8*)&lsA[ar * 64 + ((kg ^ (ar & 7)) * 8)];
      }
#pragma unroll
      for (int j = 0; j < 4; ++j) {
        const int br = wn + j * 16 + (lane & 15);
        bf[j] = *(const bf16x8*)&lsB[br * 64 + ((kg ^ (br & 7)) * 8)];
      }
#pragma unroll
      for (int i = 0; i < 8; ++i)
#pragma unroll
        for (int j = 0; j < 4; ++j)
          acc[i][j] = __builtin_amdgcn_mfma_f32_16x16x32_bf16(af[i], bf[j], acc[i][j], 0, 0, 0);
    }
  }

  // epilogue: plain bf16 stores into pair-row buffer (gate already in h)
#pragma unroll
  for (int i = 0; i < 8; ++i) {
#pragma unroll
    for (int r = 0; r < 4; ++r) {
      const int lrow = m0 + wm + i * 16 + (lane >> 4) * 4 + r;
      if (lrow < cnte) {
        uint16_t* yp = y + (size_t)(be + lrow) * H_DIM + n0 + wn + (lane & 15);
#pragma unroll
        for (int j = 0; j < 4; ++j)
          yp[j * 16] = f2bf(acc[i][j][r]);
      }
    }
  }
}

// ---------------- combine: out[t] = y[slot1(t)] + y[slot2(t)]  (fp32 out)
__global__ __launch_bounds__(256) void combine_k(
    const uint16_t* __restrict__ y, const int* __restrict__ tokSlot,
    const int* __restrict__ base, float* __restrict__ out)
{
  const int t = blockIdx.x * 2 + (threadIdx.x >> 7);   // 128 threads per token
  const int c = (threadIdx.x & 127) * 8;
  const int4 s = ((const int4*)tokSlot)[t];
  const uint16_t* y1 = y + (size_t)(base[s.x] + s.y) * H_DIM + c;
  const uint16_t* y2 = y + (size_t)(base[s.z] + s.w) * H_DIM + c;
  const u16x8 a = *(const u16x8*)y1;
  const u16x8 b = *(const u16x8*)y2;
  float* op = out + (size_t)t * H_DIM + c;
  f32x4 o0, o1;
#pragma unroll
  for (int j = 0; j < 4; ++j) {
    o0[j] = __bfloat162float(__hip_bfloat16_raw{a[j]}) +
            __bfloat162float(__hip_bfloat16_raw{b[j]});
    o1[j] = __bfloat162float(__hip_bfloat16_raw{a[j + 4]}) +
            __bfloat162float(__hip_bfloat16_raw{b[j + 4]});
  }
  *(f32x4*)op       = o0;
  *(f32x4*)(op + 4) = o1;
}

extern "C" void kernel_launch(void* const* d_in, const int* in_sizes, int n_in,
                              void* d_out, int out_size, void* d_ws, size_t ws_size,
                              hipStream_t stream)
{
  const float* x  = (const float*)d_in[0];
  const float* wr = (const float*)d_in[1];
  const float* w1 = (const float*)d_in[2];
  const float* w2 = (const float*)d_in[3];
  const float* w3 = (const float*)d_in[4];
  float* out    = (float*)d_out;
  float* logits = out + (size_t)T_TOK * H_DIM;

  uint8_t* ws = (uint8_t*)d_ws;
  const size_t PADROWS  = (size_t)MG_BLKS * 256;                    // 10240
  const size_t XB_OFF   = 0;                                        // bf16 x   [T][H]      8 MB
  const size_t HB_OFF   = XB_OFF + (size_t)T_TOK * H_DIM * 2;       // bf16 h   [10240][F] 80 MB
  const size_t Y_OFF    = HB_OFF + PADROWS * F_DIM * 2;             // bf16 y   [10240][H] 20 MB
  const size_t PT_OFF   = Y_OFF + PADROWS * H_DIM * 2;
  const size_t PG_OFF   = PT_OFF + (size_t)NE * T_TOK * 4;
  const size_t TS_OFF   = PG_OFF + (size_t)NE * T_TOK * 4;          // int4 tokSlot [T]
  const size_t CNT_OFF  = TS_OFF + (size_t)T_TOK * 16;
  const size_t BASE_OFF = CNT_OFF + 64;
  const size_t NEED     = BASE_OFF + 64;
  if (ws_size < NEED) return;

  uint16_t* xb      = (uint16_t*)(ws + XB_OFF);
  uint16_t* hb      = (uint16_t*)(ws + HB_OFF);
  uint16_t* yb      = (uint16_t*)(ws + Y_OFF);
  int*      pairTok = (int*)(ws + PT_OFF);
  float*    pairGate= (float*)(ws + PG_OFF);
  int*      tokSlot = (int*)(ws + TS_OFF);
  int*      cnt     = (int*)(ws + CNT_OFF);
  int*      basep   = (int*)(ws + BASE_OFF);

  hipMemsetAsync(cnt, 0, 64, stream);
  router_k<<<T_TOK / 4, 256, 0, stream>>>(x, wr, logits, xb, pairTok, pairGate, tokSlot, cnt);
  prefix_k<<<1, 64, 0, stream>>>(cnt, basep);
  ffn1_k<<<dim3(F_DIM / 64, MG_BLKS, 1), 256, 0, stream>>>(xb, w1, w3, hb, pairTok, pairGate, cnt, basep);
  ffn2_k<<<dim3(H_DIM / 128, MG_BLKS, 1), 256, 0, stream>>>(hb, w2, yb, cnt, basep);
  combine_k<<<T_TOK / 2, 256, 0, stream>>>(yb, tokSlot, basep, out);
}